// Round 15
// baseline (504.647 us; speedup 1.0000x reference)
//
#include <hip/hip_runtime.h>
#include <hip/hip_bf16.h>

// ============ DIAGNOSTIC ROUND ============
// Same pipeline as R14, but every kernel repeats its idempotent work rep*x
// (runtime arg + asm memory barrier, so no DCE) to push each dispatch past
// the 45us top-5 threshold: per-kernel cost = dur/rep, gaps from timestamps.
// REVERT reps next round.

typedef unsigned short u16;
typedef unsigned int   u32;
typedef __attribute__((ext_vector_type(8))) short bf16x8;
typedef __attribute__((ext_vector_type(4))) float f32x4;

#define N_NODES 4096
#define E_EDGES 131072
#define AS1 __attribute__((address_space(1)))
#define AS3 __attribute__((address_space(3)))

__device__ __forceinline__ u16 f2bf(float f) {
    u32 u = __float_as_uint(f);
    return (u16)((u + 0x7FFFu + ((u >> 16) & 1u)) >> 16);
}
__device__ __forceinline__ float bflo(u32 w) { return __uint_as_float(w << 16); }
__device__ __forceinline__ float bfhi(u32 w) { return __uint_as_float(w & 0xffff0000u); }

__device__ __forceinline__ void pack_body(const float* __restrict__ in,
                                          u16* __restrict__ hi, int K, int kcs, int gid)
{
    const int r   = gid & 63;
    const int kb  = (gid >> 6) & 7;
    const int pkc = gid >> 9;
    const int kc  = pkc & ((1 << kcs) - 1);
    const int p   = pkc >> kcs;
    const size_t row = ((size_t)p << 6) | r;
    const int k0 = (kc << 6) | (kb << 3);

    const float* src = in + row * (size_t)K + k0;
    const float4 v0 = *(const float4*)src;
    const float4 v1 = *(const float4*)(src + 4);
    const float vv[8] = {v0.x, v0.y, v0.z, v0.w, v1.x, v1.y, v1.z, v1.w};

    u32 hw[4];
    #pragma unroll
    for (int q = 0; q < 4; ++q)
        hw[q] = (u32)f2bf(vv[2 * q]) | ((u32)f2bf(vv[2 * q + 1]) << 16);
    uint4 hv = {hw[0], hw[1], hw[2], hw[3]};
    *(uint4*)(hi + (size_t)gid * 8) = hv;
}

// ---------------------------------------------------------------------------
__global__ __launch_bounds__(256)
void prep_weights(const float* __restrict__ W1, const float* __restrict__ We1,
                  const float* __restrict__ W2, const float* __restrict__ b2,
                  const float* __restrict__ be1,
                  u16* __restrict__ w1h, u16* __restrict__ wabh,
                  float* __restrict__ bab, int rep)
{
    const int bid = blockIdx.x;
    for (int rr = 0; rr < rep; ++rr) {
        if (bid < 128) {
            pack_body(W1, w1h, 1024, 4, bid * 256 + threadIdx.x);
        } else if (bid < 192) {
            const int r0 = (bid - 128) * 8;
            const int c  = threadIdx.x;
            float acc[8] = {};
            for (int k = 0; k < 256; ++k) {
                const float w2 = W2[k * 256 + c];
                #pragma unroll
                for (int j = 0; j < 8; ++j) {
                    const int r = r0 + j;
                    acc[j] += We1[(size_t)(r & 255) * 512 + ((r >> 8) << 8) + k] * w2;
                }
            }
            const int kc = c >> 6, kb = (c >> 3) & 7, e = c & 7;
            #pragma unroll
            for (int j = 0; j < 8; ++j) {
                const int r = r0 + j;
                wabh[(((((size_t)(r >> 6) << 2) + kc) << 3) + kb) * 512
                     + (size_t)(r & 63) * 8 + e] = f2bf(acc[j]);
            }
        } else {
            const int r = (bid - 192) * 256 + threadIdx.x;
            const int i = r & 255;
            const int koff = (r >> 8) << 8;
            float acc = (r < 256) ? be1[i] : 0.0f;
            for (int k = 0; k < 256; k += 4) {
                const float4 w = *(const float4*)(We1 + (size_t)i * 512 + koff + k);
                const float4 b = *(const float4*)(b2 + k);
                acc += w.x * b.x + w.y * b.y + w.z * b.z + w.w * b.w;
            }
            bab[r] = acc;
        }
        asm volatile("" ::: "memory");
    }
}

// ---------------------------------------------------------------------------
__global__ __launch_bounds__(256, 2)
void gemm_fused(const float* __restrict__ X, const u16* __restrict__ W1p,
                const u16* __restrict__ Wabp, const float* __restrict__ b1,
                const float* __restrict__ bab, u16* __restrict__ ABout, int rep)
{
    __shared__ u16 As[2][1024];
    __shared__ u16 Bs[2][16384];
    __shared__ u16 H1[4096];
    const int tid  = threadIdx.x;
    const int wv   = tid >> 6;
    const int lane = tid & 63;
    const int kq   = lane >> 4;
    const int r16  = lane & 15;
    const int rowbase = blockIdx.x << 4;

    const int arow = tid & 15;
    const int akb  = tid >> 4;
    const float* gx = X + (size_t)(rowbase + arow) * 1024 + (akb << 3);

    for (int rr = 0; rr < rep; ++rr) {
        float4 ra0, ra1;
        auto regloadA = [&](int t) {
            if (tid < 128) {
                const float* p = gx + t * 64;
                ra0 = *(const float4*)p;
                ra1 = *(const float4*)(p + 4);
            }
        };
        auto storeA = [&](int b) {
            if (tid < 128) {
                const float av[8] = {ra0.x, ra0.y, ra0.z, ra0.w,
                                     ra1.x, ra1.y, ra1.z, ra1.w};
                u32 w[4];
                #pragma unroll
                for (int q = 0; q < 4; ++q)
                    w[q] = (u32)f2bf(av[2 * q]) | ((u32)f2bf(av[2 * q + 1]) << 16);
                uint4 v = {w[0], w[1], w[2], w[3]};
                *(uint4*)&As[b][((akb << 4) + arow) << 3] = v;
            }
        };
        auto stageW = [&](int b, int t) {
            #pragma unroll
            for (int pan = 0; pan < 4; ++pan) {
                const u16* gw = W1p + (((size_t)pan * 16 + t) << 12);
                #pragma unroll
                for (int c = 0; c < 2; ++c) {
                    const int ch = (wv << 1) + c;
                    __builtin_amdgcn_global_load_lds(
                        (const AS1 u32*)(gw + (ch << 9) + (lane << 3)),
                        (AS3 u32*)(&Bs[b][(pan << 12) + (ch << 9) + (lane << 3)]),
                        16, 0, 0);
                }
            }
        };

        f32x4 acc[4];
        #pragma unroll
        for (int n = 0; n < 4; ++n) acc[n] = (f32x4){0.f, 0.f, 0.f, 0.f};

        auto compute1 = [&](int b) {
            #pragma unroll
            for (int s = 0; s < 2; ++s) {
                const int kb = (s << 2) + kq;
                const bf16x8 af = *(const bf16x8*)&As[b][((kb << 4) + r16) << 3];
                #pragma unroll
                for (int n = 0; n < 4; ++n) {
                    const bf16x8 bf = *(const bf16x8*)
                        &Bs[b][(wv << 12) + (((kb << 6) + (n << 4) + r16) << 3)];
                    acc[n] = __builtin_amdgcn_mfma_f32_16x16x32_bf16(af, bf, acc[n], 0, 0, 0);
                }
            }
        };

        stageW(0, 0);
        regloadA(0);
        storeA(0);
        __syncthreads();
        int buf = 0;
        for (int t = 0; t < 16; ++t) {
            if (t + 1 < 16) { stageW(buf ^ 1, t + 1); regloadA(t + 1); }
            compute1(buf);
            if (t + 1 < 16) storeA(buf ^ 1);
            __syncthreads();
            buf ^= 1;
        }

        #pragma unroll
        for (int n = 0; n < 4; ++n) {
            const int c  = (wv << 6) + (n << 4) + r16;
            const float bv = b1[c];
            const int kb2 = (wv << 3) + (n << 1) + (r16 >> 3);
            #pragma unroll
            for (int j = 0; j < 4; ++j) {
                const float v = fmaxf(acc[n][j] + bv, 0.0f);
                H1[(((kb2 << 4) + (kq << 2) + j) << 3) + (r16 & 7)] = f2bf(v);
            }
        }
        __syncthreads();

        f32x4 acc2[2][4];
        #pragma unroll
        for (int p2 = 0; p2 < 2; ++p2)
            #pragma unroll
            for (int n = 0; n < 4; ++n) acc2[p2][n] = (f32x4){0.f, 0.f, 0.f, 0.f};

        for (int t = 0; t < 4; ++t) {
            #pragma unroll
            for (int s = 0; s < 2; ++s) {
                const int kb32 = ((((t << 1) + s) << 2) + kq);
                const bf16x8 af = *(const bf16x8*)&H1[((kb32 << 4) + r16) << 3];
                #pragma unroll
                for (int p2 = 0; p2 < 2; ++p2) {
                    const int bn = (wv << 1) + p2;
                    const u16* wb = Wabp + ((((size_t)bn << 2) + t) * 8 + (s << 2) + kq) * 512;
                    #pragma unroll
                    for (int n = 0; n < 4; ++n) {
                        const bf16x8 bf = *(const bf16x8*)(wb + (((n << 4) + r16) << 3));
                        acc2[p2][n] = __builtin_amdgcn_mfma_f32_16x16x32_bf16(af, bf, acc2[p2][n], 0, 0, 0);
                    }
                }
            }
        }

        #pragma unroll
        for (int p2 = 0; p2 < 2; ++p2)
            #pragma unroll
            for (int n = 0; n < 4; ++n) {
                const int col = (wv << 7) + (p2 << 6) + (n << 4) + r16;
                const float bv = bab[col];
                #pragma unroll
                for (int j = 0; j < 4; ++j) {
                    const int row = rowbase + (kq << 2) + j;
                    ABout[(size_t)row * 512 + col] = f2bf(acc2[p2][n][j] + bv);
                }
            }
        __syncthreads();
        asm volatile("" ::: "memory");
    }
}

// ---------------------------------------------------------------------------
__global__ __launch_bounds__(256)
void edge_fill(const u16* __restrict__ AB, const int* __restrict__ idx,
               const float* __restrict__ We2, const float* __restrict__ be2p,
               float* __restrict__ vbuf, float* __restrict__ part,
               float4* __restrict__ out4, int rep)
{
    const int bid = blockIdx.x;
    const int tid = threadIdx.x;

    if (bid < 512) {
        for (int rr = 0; rr < rep; ++rr) {
            float4* op = out4 + (size_t)bid * 8192 + tid;
            const float4 z = {0.f, 0.f, 0.f, 0.f};
            #pragma unroll 8
            for (int q = 0; q < 32; ++q)
                op[(size_t)q * 256] = z;
            asm volatile("" ::: "memory");
        }
        return;
    }

    __shared__ float sm[256];
    const int cb   = bid - 512;
    const int lane = tid & 63;
    const int sub  = lane >> 5;
    const int l5   = lane & 31;
    const int wid  = (cb * 256 + tid) >> 6;
    const float be2 = be2p[0];

    float w2v[8];
    #pragma unroll
    for (int q = 0; q < 2; ++q) {
        const float4 w = ((const float4*)We2)[l5 * 2 + q];
        w2v[q * 4 + 0] = w.x; w2v[q * 4 + 1] = w.y;
        w2v[q * 4 + 2] = w.z; w2v[q * 4 + 3] = w.w;
    }

    for (int rr = 0; rr < rep; ++rr) {
        float zloc = 0.0f;
        #pragma unroll
        for (int it = 0; it < 8; ++it) {
            const int e = (wid << 1) + sub + (it << 14);
            const int src = idx[2 * e];
            const int dst = idx[2 * e + 1];
            const uint4 av = *(const uint4*)(AB + ((size_t)src << 9) + (l5 << 3));
            const uint4 bv = *(const uint4*)(AB + ((size_t)dst << 9) + 256 + (l5 << 3));
            const u32 aw[4] = {av.x, av.y, av.z, av.w};
            const u32 bw[4] = {bv.x, bv.y, bv.z, bv.w};
            float p = 0.0f;
            #pragma unroll
            for (int q = 0; q < 4; ++q) {
                p += fmaxf(bflo(aw[q]) + bflo(bw[q]), 0.0f) * w2v[2 * q];
                p += fmaxf(bfhi(aw[q]) + bfhi(bw[q]), 0.0f) * w2v[2 * q + 1];
            }
            #pragma unroll
            for (int m = 16; m > 0; m >>= 1)
                p += __shfl_xor(p, m, 64);
            const float v = expf(p + be2);
            if (l5 == 0) {
                vbuf[e] = v;
                zloc += v;
            }
        }
        sm[tid] = zloc;
        __syncthreads();
        for (int st = 128; st > 0; st >>= 1) {
            if (tid < st) sm[tid] += sm[tid + st];
            __syncthreads();
        }
        if (tid == 0) part[cb] = sm[0];
        __syncthreads();
        asm volatile("" ::: "memory");
    }
}

// ---------------------------------------------------------------------------
__global__ __launch_bounds__(256)
void scatter_probs(const float* __restrict__ vbuf, const int* __restrict__ idx,
                   const float* __restrict__ part, float* __restrict__ out,
                   int n, int rep)
{
    __shared__ float sm[256];
    for (int rr = 0; rr < rep; ++rr) {
        float a = part[threadIdx.x];
        #pragma unroll
        for (int k = 1; k < 8; ++k)
            a += part[threadIdx.x + k * 256];
        sm[threadIdx.x] = a;
        __syncthreads();
        for (int st = 128; st > 0; st >>= 1) {
            if (threadIdx.x < st) sm[threadIdx.x] += sm[threadIdx.x + st];
            __syncthreads();
        }
        const float Z = sm[0];
        const int e = blockIdx.x * 256 + threadIdx.x;
        if (e < n)
            out[(size_t)idx[2 * e] * N_NODES + idx[2 * e + 1]] = vbuf[e] / Z;
        __syncthreads();
        asm volatile("" ::: "memory");
    }
}

// ---------------------------------------------------------------------------
extern "C" void kernel_launch(void* const* d_in, const int* in_sizes, int n_in,
                              void* d_out, int out_size, void* d_ws, size_t ws_size,
                              hipStream_t stream)
{
    const float* ideal = (const float*)d_in[0];
    const int*   idx   = (const int*)d_in[1];
    const float* W1    = (const float*)d_in[2];
    const float* b1    = (const float*)d_in[3];
    const float* W2    = (const float*)d_in[4];
    const float* b2    = (const float*)d_in[5];
    const float* We1   = (const float*)d_in[6];
    const float* be1   = (const float*)d_in[7];
    const float* We2   = (const float*)d_in[8];
    const float* be2   = (const float*)d_in[9];
    float* out = (float*)d_out;

    char* Wb = (char*)d_ws;
    u16*   w1h  = (u16*)(Wb);
    u16*   wabh = (u16*)(Wb + (512u << 10));
    float* bab  = (float*)(Wb + (768u << 10));
    u16*   ABbf = (u16*)(Wb + (1u << 20));
    float* vbuf = (float*)(Wb + (6u << 20));
    float* part = vbuf + E_EDGES;

    // DIAGNOSTIC rep factors: push each dispatch past the 45us top-5 bar.
    prep_weights<<<194, 256, 0, stream>>>(W1, We1, W2, b2, be1, w1h, wabh, bab, 20);
    gemm_fused<<<256, 256, 0, stream>>>(ideal, w1h, wabh, b1, bab, ABbf, 8);
    edge_fill<<<2560, 256, 0, stream>>>(ABbf, idx, We2, be2, vbuf, part, (float4*)out, 6);
    scatter_probs<<<512, 256, 0, stream>>>(vbuf, idx, part, out, E_EDGES, 16);
}

// Round 16
// 71.921 us; speedup vs baseline: 7.0166x; 7.0166x over previous
//
#include <hip/hip_runtime.h>
#include <hip/hip_bf16.h>

// TwinPolicy, pure-bf16 MFMA pipeline (5 launches):
//   prep_all: pack x -> xh, pack W1 -> w1h, fold Wab=(We1@W2) -> wabh, bab
//   gemm1: h1p = pack(relu(x @ W1.T + b1))  BM=BN=32, grid(128,8)=1024 blocks
//   gemm2: ABbf = bf16(h1 @ Wab.T + bab)    BM=BN=32, grid(128,16)=2048 blocks
//     (R15 diagnostic: fused 256-block gemm = 27.5us at MfmaUtil 4.6%,
//      Occupancy 11% -- latency-bound at 1 block/CU. Fix = small tiles,
//      many blocks: TLP hides staging latency.)
//   edge_fill (block-specialized): blocks 0..511 zero-fill 67MB output;
//     blocks 512..2559 compute v[e]=exp(s[e]) + block partial Z
//   scatter_probs: redundant Z-reduce per block + out[src,dst] = v/Z

typedef unsigned short u16;
typedef unsigned int   u32;
typedef __attribute__((ext_vector_type(8))) short bf16x8;
typedef __attribute__((ext_vector_type(4))) float f32x4;

#define N_NODES 4096
#define E_EDGES 131072
#define AS1 __attribute__((address_space(1)))
#define AS3 __attribute__((address_space(3)))

__device__ __forceinline__ u16 f2bf(float f) {
    u32 u = __float_as_uint(f);
    return (u16)((u + 0x7FFFu + ((u >> 16) & 1u)) >> 16);
}
__device__ __forceinline__ float bflo(u32 w) { return __uint_as_float(w << 16); }
__device__ __forceinline__ float bfhi(u32 w) { return __uint_as_float(w & 0xffff0000u); }

// ---------------------------------------------------------------------------
// Pack f32 [M][K] -> bf16, MFMA-ready layout:
// elem(row,k) -> ((((row>>6)*KC + (k>>6))*8 + ((k>>3)&7))*64 + (row&63))*8 + (k&7)
// ---------------------------------------------------------------------------
__device__ __forceinline__ void pack_body(const float* __restrict__ in,
                                          u16* __restrict__ hi, int K, int kcs, int gid)
{
    const int r   = gid & 63;
    const int kb  = (gid >> 6) & 7;
    const int pkc = gid >> 9;
    const int kc  = pkc & ((1 << kcs) - 1);
    const int p   = pkc >> kcs;
    const size_t row = ((size_t)p << 6) | r;
    const int k0 = (kc << 6) | (kb << 3);

    const float* src = in + row * (size_t)K + k0;
    const float4 v0 = *(const float4*)src;
    const float4 v1 = *(const float4*)(src + 4);
    const float vv[8] = {v0.x, v0.y, v0.z, v0.w, v1.x, v1.y, v1.z, v1.w};

    u32 hw[4];
    #pragma unroll
    for (int q = 0; q < 4; ++q)
        hw[q] = (u32)f2bf(vv[2 * q]) | ((u32)f2bf(vv[2 * q + 1]) << 16);
    uint4 hv = {hw[0], hw[1], hw[2], hw[3]};
    *(uint4*)(hi + (size_t)gid * 8) = hv;
}

// ---------------------------------------------------------------------------
// prep_all (2242 blocks):
//   [0,2048):     pack ideal (4096x1024) -> xh
//   [2048,2176):  pack W1 (256x1024) -> w1h
//   [2176,2240):  Wab[r][c] = (r<256 ? We1a@W2 : We1b@W2), packed bf16 W-layout
//   [2240,2242):  bab[r] = (r<256 ? be1[r] : 0) + dot(We1 row-part, b2)
// ---------------------------------------------------------------------------
__global__ __launch_bounds__(256)
void prep_all(const float* __restrict__ ideal, const float* __restrict__ W1,
              const float* __restrict__ We1, const float* __restrict__ W2,
              const float* __restrict__ b2, const float* __restrict__ be1,
              u16* __restrict__ xh, u16* __restrict__ w1h,
              u16* __restrict__ wabh, float* __restrict__ bab)
{
    const int bid = blockIdx.x;
    if (bid < 2048) {
        pack_body(ideal, xh, 1024, 4, bid * 256 + threadIdx.x);
    } else if (bid < 2176) {
        pack_body(W1, w1h, 1024, 4, (bid - 2048) * 256 + threadIdx.x);
    } else if (bid < 2240) {
        const int r0 = (bid - 2176) * 8;
        const int c  = threadIdx.x;
        float acc[8] = {};
        for (int k = 0; k < 256; ++k) {
            const float w2 = W2[k * 256 + c];
            #pragma unroll
            for (int j = 0; j < 8; ++j) {
                const int r = r0 + j;
                acc[j] += We1[(size_t)(r & 255) * 512 + ((r >> 8) << 8) + k] * w2;
            }
        }
        const int kc = c >> 6, kb = (c >> 3) & 7, e = c & 7;
        #pragma unroll
        for (int j = 0; j < 8; ++j) {
            const int r = r0 + j;
            wabh[(((((size_t)(r >> 6) << 2) + kc) << 3) + kb) * 512 + (size_t)(r & 63) * 8 + e]
                = f2bf(acc[j]);
        }
    } else {
        const int r = (bid - 2240) * 256 + threadIdx.x;
        const int i = r & 255;
        const int koff = (r >> 8) << 8;
        float acc = (r < 256) ? be1[i] : 0.0f;
        for (int k = 0; k < 256; k += 4) {
            const float4 w = *(const float4*)(We1 + (size_t)i * 512 + koff + k);
            const float4 b = *(const float4*)(b2 + k);
            acc += w.x * b.x + w.y * b.y + w.z * b.z + w.w * b.w;
        }
        bab[r] = acc;
    }
}

// ---------------------------------------------------------------------------
// 32x32-tile MFMA GEMM, 4 waves (wave = 16x16 quadrant, wr=wv>>1, wc=wv&1).
// A, W packed bf16 in 64-panel layout; BK=64; double-buffered LDS (16 KB).
// CMODE 0: epilogue relu+bias -> packed A-layout for a K=256 next GEMM.
// CMODE 1: epilogue bias -> bf16 row-major [M][512].
// grid: (M/32, Nout/32).  K-order (t asc, s asc, kb=s*4+kq) == R11 exactly.
// ---------------------------------------------------------------------------
template<int KC, int CMODE>
__global__ __launch_bounds__(256)
void mfma_gemm32(const u16* __restrict__ A, const u16* __restrict__ W,
                 const float* __restrict__ bias, u16* __restrict__ Cout)
{
    __shared__ u16 As[2][2048];   // [kb8][r32][e8] = 4 KB
    __shared__ u16 Bs[2][2048];
    const int tid  = threadIdx.x;
    const int wv   = tid >> 6;
    const int lane = tid & 63;
    const int kq   = lane >> 4;
    const int r16  = lane & 15;
    const int wr   = wv >> 1;
    const int wc   = wv & 1;
    const int bp   = blockIdx.x;              // row-block of 32
    const int bn   = blockIdx.y;              // col-block of 32
    const int p    = bp >> 1, r0 = (bp & 1) << 5;   // source 64-row panel
    const int pn   = bn >> 1, c0 = (bn & 1) << 5;   // source 64-col panel

    const int skb = tid >> 5;                 // staging: kb 0..7
    const int srSan = tid & 31;               // staging: row/col 0..31

    auto stage = [&](int b, int t) {
        const u16* ga = A + (((size_t)p * KC + t) << 12) + (skb << 9)
                          + ((size_t)(r0 + srSan) << 3);
        __builtin_amdgcn_global_load_lds((const AS1 u32*)ga,
            (AS3 u32*)(&As[b][tid << 3]), 16, 0, 0);
        const u16* gw = W + (((size_t)pn * KC + t) << 12) + (skb << 9)
                          + ((size_t)(c0 + srSan) << 3);
        __builtin_amdgcn_global_load_lds((const AS1 u32*)gw,
            (AS3 u32*)(&Bs[b][tid << 3]), 16, 0, 0);
    };

    f32x4 acc = (f32x4){0.f, 0.f, 0.f, 0.f};

    auto compute = [&](int b) {
        #pragma unroll
        for (int s = 0; s < 2; ++s) {
            const int kb = (s << 2) + kq;
            const bf16x8 af = *(const bf16x8*)&As[b][((kb << 5) + (wr << 4) + r16) << 3];
            const bf16x8 bf = *(const bf16x8*)&Bs[b][((kb << 5) + (wc << 4) + r16) << 3];
            acc = __builtin_amdgcn_mfma_f32_16x16x32_bf16(af, bf, acc, 0, 0, 0);
        }
    };

    stage(0, 0);
    __syncthreads();
    int buf = 0;
    for (int t = 0; t < KC; ++t) {
        if (t + 1 < KC) stage(buf ^ 1, t + 1);
        compute(buf);
        __syncthreads();
        buf ^= 1;
    }

    // C/D: col=lane&15, row=(lane>>4)*4+j  within the wave's 16x16 quadrant.
    const int cl = (wc << 4) + r16;           // local col 0..31
    const int C  = (bn << 5) + cl;            // global out col
    const float bv = bias[C];
    if constexpr (CMODE == 0) {
        // packed A-layout for next GEMM (K=256 -> 4 k-chunks):
        // idx = (((row>>6)*4 + (C>>6))*8 + ((C>>3)&7))*512 + (row&63)*8 + (C&7)
        const int kcn = C >> 6;
        const int kb2 = (C >> 3) & 7;
        const int e2  = C & 7;
        #pragma unroll
        for (int j = 0; j < 4; ++j) {
            const int row = (bp << 5) + (wr << 4) + (kq << 2) + j;
            const float v = fmaxf(acc[j] + bv, 0.0f);
            Cout[((((size_t)(row >> 6) << 2) + kcn) * 8 + kb2) * 512
                 + (size_t)(row & 63) * 8 + e2] = f2bf(v);
        }
    } else {
        #pragma unroll
        for (int j = 0; j < 4; ++j) {
            const int row = (bp << 5) + (wr << 4) + (kq << 2) + j;
            Cout[(size_t)row * 512 + C] = f2bf(acc[j] + bv);
        }
    }
}

// ---------------------------------------------------------------------------
// Block-specialized edge + fill (NO inter-block sync needed):
//   blocks [0,512):    zero-fill 67MB output (32 float4/thread)
//   blocks [512,2560): v[e] = exp(score[e]) (no max-sub; |s| = O(1)),
//                      block-partial Z -> part[cb] (only l5==0 lanes add).
// ---------------------------------------------------------------------------
__global__ __launch_bounds__(256)
void edge_fill(const u16* __restrict__ AB, const int* __restrict__ idx,
               const float* __restrict__ We2, const float* __restrict__ be2p,
               float* __restrict__ vbuf, float* __restrict__ part,
               float4* __restrict__ out4)
{
    const int bid = blockIdx.x;
    const int tid = threadIdx.x;

    if (bid < 512) {
        float4* op = out4 + (size_t)bid * 8192 + tid;
        const float4 z = {0.f, 0.f, 0.f, 0.f};
        #pragma unroll 8
        for (int q = 0; q < 32; ++q)
            op[(size_t)q * 256] = z;
        return;
    }

    __shared__ float sm[256];
    const int cb   = bid - 512;                  // 0..2047
    const int lane = tid & 63;
    const int sub  = lane >> 5;
    const int l5   = lane & 31;
    const int wid  = (cb * 256 + tid) >> 6;      // 0..8191
    const float be2 = be2p[0];

    float w2v[8];
    #pragma unroll
    for (int q = 0; q < 2; ++q) {
        const float4 w = ((const float4*)We2)[l5 * 2 + q];
        w2v[q * 4 + 0] = w.x; w2v[q * 4 + 1] = w.y;
        w2v[q * 4 + 2] = w.z; w2v[q * 4 + 3] = w.w;
    }

    float zloc = 0.0f;
    #pragma unroll
    for (int it = 0; it < 8; ++it) {
        const int e = (wid << 1) + sub + (it << 14);    // covers [0, 131072)
        const int src = idx[2 * e];
        const int dst = idx[2 * e + 1];
        const uint4 av = *(const uint4*)(AB + ((size_t)src << 9) + (l5 << 3));
        const uint4 bv = *(const uint4*)(AB + ((size_t)dst << 9) + 256 + (l5 << 3));
        const u32 aw[4] = {av.x, av.y, av.z, av.w};
        const u32 bw[4] = {bv.x, bv.y, bv.z, bv.w};
        float p = 0.0f;
        #pragma unroll
        for (int q = 0; q < 4; ++q) {
            p += fmaxf(bflo(aw[q]) + bflo(bw[q]), 0.0f) * w2v[2 * q];
            p += fmaxf(bfhi(aw[q]) + bfhi(bw[q]), 0.0f) * w2v[2 * q + 1];
        }
        #pragma unroll
        for (int m = 16; m > 0; m >>= 1)
            p += __shfl_xor(p, m, 64);   // xor<32: stays within the half-wave
        const float v = expf(p + be2);
        if (l5 == 0) {
            vbuf[e] = v;
            zloc += v;                   // one lane per edge contributes
        }
    }
    sm[tid] = zloc;
    __syncthreads();
    for (int st = 128; st > 0; st >>= 1) {
        if (tid < st) sm[tid] += sm[tid + st];
        __syncthreads();
    }
    if (tid == 0) part[cb] = sm[0];
}

// fused: finalize Z over part[2048] (redundant per block) + scatter probs
__global__ __launch_bounds__(256)
void scatter_probs(const float* __restrict__ vbuf, const int* __restrict__ idx,
                   const float* __restrict__ part, float* __restrict__ out, int n)
{
    __shared__ float sm[256];
    float a = part[threadIdx.x];
    #pragma unroll
    for (int k = 1; k < 8; ++k)
        a += part[threadIdx.x + k * 256];
    sm[threadIdx.x] = a;
    __syncthreads();
    for (int st = 128; st > 0; st >>= 1) {
        if (threadIdx.x < st) sm[threadIdx.x] += sm[threadIdx.x + st];
        __syncthreads();
    }
    const float Z = sm[0];
    const int e = blockIdx.x * 256 + threadIdx.x;
    if (e < n)
        out[(size_t)idx[2 * e] * N_NODES + idx[2 * e + 1]] = vbuf[e] / Z;
}

// ---------------------------------------------------------------------------
extern "C" void kernel_launch(void* const* d_in, const int* in_sizes, int n_in,
                              void* d_out, int out_size, void* d_ws, size_t ws_size,
                              hipStream_t stream)
{
    const float* ideal = (const float*)d_in[0];   // 4096 x 1024
    const int*   idx   = (const int*)d_in[1];     // E x 2
    const float* W1    = (const float*)d_in[2];   // 256 x 1024
    const float* b1    = (const float*)d_in[3];   // 256
    const float* W2    = (const float*)d_in[4];   // 256 x 256
    const float* b2    = (const float*)d_in[5];   // 256
    const float* We1   = (const float*)d_in[6];   // 256 x 512
    const float* be1   = (const float*)d_in[7];   // 256
    const float* We2   = (const float*)d_in[8];   // 256
    const float* be2   = (const float*)d_in[9];   // 1
    float* out = (float*)d_out;

    char* Wb = (char*)d_ws;
    u16*   xh   = (u16*)(Wb);                          // 8 MB packed x
    u16*   w1h  = (u16*)(Wb + (8u << 20));             // 512 KB packed W1
    u16*   wabh = (u16*)(Wb + (8u << 20) + (512u << 10)); // 256 KB packed Wab
    u16*   h1h  = (u16*)(Wb + (9u << 20));             // 2 MB packed h1
    float* bab  = (float*)(Wb + (11u << 20));          // 2 KB
    u16*   ABbf = (u16*)(Wb + (12u << 20));            // 4 MB bf16 AB row-major
    float* vbuf = (float*)(Wb + (16u << 20));          // 512 KB exp(scores)
    float* part = vbuf + E_EDGES;                      // 2048 partial Z

    prep_all<<<2242, 256, 0, stream>>>(ideal, W1, We1, W2, b2, be1, xh, w1h, wabh, bab);

    // h1 packed = relu(x @ W1.T + b1)   (1024 blocks, 4/CU)
    mfma_gemm32<16, 0><<<dim3(128, 8), 256, 0, stream>>>(xh, w1h, b1, h1h);
    // AB bf16 = h1 @ Wab.T + bab        (2048 blocks, 8/CU)
    mfma_gemm32<4, 1><<<dim3(128, 16), 256, 0, stream>>>(h1h, wabh, bab, ABbf);

    // fill (512 blocks) + exp(scores) + partial Z (2048 blocks), no sync
    edge_fill<<<2560, 256, 0, stream>>>(ABbf, idx, We2, be2, vbuf, part, (float4*)out);
    // Z finalize (redundant per block) + scatter
    scatter_probs<<<512, 256, 0, stream>>>(vbuf, idx, part, out, E_EDGES);
}

// Round 17
// 69.916 us; speedup vs baseline: 7.2179x; 1.0287x over previous
//
#include <hip/hip_runtime.h>
#include <hip/hip_bf16.h>

// TwinPolicy, pure-bf16 MFMA pipeline (5 launches).
// R16 lesson: 32x32 tiles / high TLP fixed the gemm latency-bound (27.5us -> ~8).
// This round: the 67MB output zero-fill is split into 4 shards of 16.7MB, one
// riding at the grid-tail of each pre-scatter kernel (prep, gemm1, gemm2, edge)
// -- each hides under that kernel's non-write-bound runtime, removing the
// ~10.5us serial fill floor from the edge kernel.

typedef unsigned short u16;
typedef unsigned int   u32;
typedef __attribute__((ext_vector_type(8))) short bf16x8;
typedef __attribute__((ext_vector_type(4))) float f32x4;

#define N_NODES 4096
#define E_EDGES 131072
#define AS1 __attribute__((address_space(1)))
#define AS3 __attribute__((address_space(3)))

__device__ __forceinline__ u16 f2bf(float f) {
    u32 u = __float_as_uint(f);
    return (u16)((u + 0x7FFFu + ((u >> 16) & 1u)) >> 16);
}
__device__ __forceinline__ float bflo(u32 w) { return __uint_as_float(w << 16); }
__device__ __forceinline__ float bfhi(u32 w) { return __uint_as_float(w & 0xffff0000u); }

// fill shard s (of 4), block fb (of 128): 128*256*32 float4 = 16.77 MB
__device__ __forceinline__ void fill_shard(float4* __restrict__ out4,
                                           int shard, int fb, int tid)
{
    float4* op = out4 + (size_t)shard * 1048576 + (size_t)fb * 8192 + tid;
    const float4 z = {0.f, 0.f, 0.f, 0.f};
    #pragma unroll 8
    for (int q = 0; q < 32; ++q)
        op[(size_t)q * 256] = z;
}

// ---------------------------------------------------------------------------
// Pack f32 [M][K] -> bf16, MFMA-ready layout:
// elem(row,k) -> ((((row>>6)*KC + (k>>6))*8 + ((k>>3)&7))*64 + (row&63))*8 + (k&7)
// ---------------------------------------------------------------------------
__device__ __forceinline__ void pack_body(const float* __restrict__ in,
                                          u16* __restrict__ hi, int K, int kcs, int gid)
{
    const int r   = gid & 63;
    const int kb  = (gid >> 6) & 7;
    const int pkc = gid >> 9;
    const int kc  = pkc & ((1 << kcs) - 1);
    const int p   = pkc >> kcs;
    const size_t row = ((size_t)p << 6) | r;
    const int k0 = (kc << 6) | (kb << 3);

    const float* src = in + row * (size_t)K + k0;
    const float4 v0 = *(const float4*)src;
    const float4 v1 = *(const float4*)(src + 4);
    const float vv[8] = {v0.x, v0.y, v0.z, v0.w, v1.x, v1.y, v1.z, v1.w};

    u32 hw[4];
    #pragma unroll
    for (int q = 0; q < 4; ++q)
        hw[q] = (u32)f2bf(vv[2 * q]) | ((u32)f2bf(vv[2 * q + 1]) << 16);
    uint4 hv = {hw[0], hw[1], hw[2], hw[3]};
    *(uint4*)(hi + (size_t)gid * 8) = hv;
}

// ---------------------------------------------------------------------------
// prep_all (2242 work + 128 fill = 2370 blocks):
//   [0,2048):     pack ideal (4096x1024) -> xh
//   [2048,2176):  pack W1 (256x1024) -> w1h
//   [2176,2240):  Wab[r][c] = (r<256 ? We1a@W2 : We1b@W2), packed bf16 W-layout
//   [2240,2242):  bab[r] = (r<256 ? be1[r] : 0) + dot(We1 row-part, b2)
//   [2242,2370):  fill shard 0
// ---------------------------------------------------------------------------
__global__ __launch_bounds__(256)
void prep_all(const float* __restrict__ ideal, const float* __restrict__ W1,
              const float* __restrict__ We1, const float* __restrict__ W2,
              const float* __restrict__ b2, const float* __restrict__ be1,
              u16* __restrict__ xh, u16* __restrict__ w1h,
              u16* __restrict__ wabh, float* __restrict__ bab,
              float4* __restrict__ out4)
{
    const int bid = blockIdx.x;
    if (bid < 2048) {
        pack_body(ideal, xh, 1024, 4, bid * 256 + threadIdx.x);
    } else if (bid < 2176) {
        pack_body(W1, w1h, 1024, 4, (bid - 2048) * 256 + threadIdx.x);
    } else if (bid < 2240) {
        const int r0 = (bid - 2176) * 8;
        const int c  = threadIdx.x;
        float acc[8] = {};
        for (int k = 0; k < 256; ++k) {
            const float w2 = W2[k * 256 + c];
            #pragma unroll
            for (int j = 0; j < 8; ++j) {
                const int r = r0 + j;
                acc[j] += We1[(size_t)(r & 255) * 512 + ((r >> 8) << 8) + k] * w2;
            }
        }
        const int kc = c >> 6, kb = (c >> 3) & 7, e = c & 7;
        #pragma unroll
        for (int j = 0; j < 8; ++j) {
            const int r = r0 + j;
            wabh[(((((size_t)(r >> 6) << 2) + kc) << 3) + kb) * 512 + (size_t)(r & 63) * 8 + e]
                = f2bf(acc[j]);
        }
    } else if (bid < 2242) {
        const int r = (bid - 2240) * 256 + threadIdx.x;
        const int i = r & 255;
        const int koff = (r >> 8) << 8;
        float acc = (r < 256) ? be1[i] : 0.0f;
        for (int k = 0; k < 256; k += 4) {
            const float4 w = *(const float4*)(We1 + (size_t)i * 512 + koff + k);
            const float4 b = *(const float4*)(b2 + k);
            acc += w.x * b.x + w.y * b.y + w.z * b.z + w.w * b.w;
        }
        bab[r] = acc;
    } else {
        fill_shard(out4, 0, bid - 2242, threadIdx.x);
    }
}

// ---------------------------------------------------------------------------
// 32x32-tile MFMA GEMM, 4 waves (wave = 16x16 quadrant, wr=wv>>1, wc=wv&1).
// A, W packed bf16 in 64-panel layout; BK=64; double-buffered LDS (16 KB).
// CMODE 0: epilogue relu+bias -> packed A-layout for a K=256 next GEMM.
// CMODE 1: epilogue bias -> bf16 row-major [M][512].
// Blocks with blockIdx.y == NBY are fill blocks (shard SHARD).
// grid: (M/32, Nout/32 + 1).  K-order == R11 exactly (bit-identical).
// ---------------------------------------------------------------------------
template<int KC, int CMODE, int NBY, int SHARD>
__global__ __launch_bounds__(256)
void mfma_gemm32(const u16* __restrict__ A, const u16* __restrict__ W,
                 const float* __restrict__ bias, u16* __restrict__ Cout,
                 float4* __restrict__ out4)
{
    if (blockIdx.y == NBY) {
        fill_shard(out4, SHARD, blockIdx.x, threadIdx.x);
        return;
    }

    __shared__ u16 As[2][2048];   // [kb8][r32][e8] = 4 KB
    __shared__ u16 Bs[2][2048];
    const int tid  = threadIdx.x;
    const int wv   = tid >> 6;
    const int lane = tid & 63;
    const int kq   = lane >> 4;
    const int r16  = lane & 15;
    const int wr   = wv >> 1;
    const int wc   = wv & 1;
    const int bp   = blockIdx.x;              // row-block of 32
    const int bn   = blockIdx.y;              // col-block of 32
    const int p    = bp >> 1, r0 = (bp & 1) << 5;   // source 64-row panel
    const int pn   = bn >> 1, c0 = (bn & 1) << 5;   // source 64-col panel

    const int skb   = tid >> 5;               // staging: kb 0..7
    const int srSan = tid & 31;               // staging: row/col 0..31

    auto stage = [&](int b, int t) {
        const u16* ga = A + (((size_t)p * KC + t) << 12) + (skb << 9)
                          + ((size_t)(r0 + srSan) << 3);
        __builtin_amdgcn_global_load_lds((const AS1 u32*)ga,
            (AS3 u32*)(&As[b][tid << 3]), 16, 0, 0);
        const u16* gw = W + (((size_t)pn * KC + t) << 12) + (skb << 9)
                          + ((size_t)(c0 + srSan) << 3);
        __builtin_amdgcn_global_load_lds((const AS1 u32*)gw,
            (AS3 u32*)(&Bs[b][tid << 3]), 16, 0, 0);
    };

    f32x4 acc = (f32x4){0.f, 0.f, 0.f, 0.f};

    auto compute = [&](int b) {
        #pragma unroll
        for (int s = 0; s < 2; ++s) {
            const int kb = (s << 2) + kq;
            const bf16x8 af = *(const bf16x8*)&As[b][((kb << 5) + (wr << 4) + r16) << 3];
            const bf16x8 bf = *(const bf16x8*)&Bs[b][((kb << 5) + (wc << 4) + r16) << 3];
            acc = __builtin_amdgcn_mfma_f32_16x16x32_bf16(af, bf, acc, 0, 0, 0);
        }
    };

    stage(0, 0);
    __syncthreads();
    int buf = 0;
    for (int t = 0; t < KC; ++t) {
        if (t + 1 < KC) stage(buf ^ 1, t + 1);
        compute(buf);
        __syncthreads();
        buf ^= 1;
    }

    // C/D: col=lane&15, row=(lane>>4)*4+j within the wave's 16x16 quadrant.
    const int cl = (wc << 4) + r16;           // local col 0..31
    const int C  = (bn << 5) + cl;            // global out col
    const float bv = bias[C];
    if constexpr (CMODE == 0) {
        const int kcn = C >> 6;
        const int kb2 = (C >> 3) & 7;
        const int e2  = C & 7;
        #pragma unroll
        for (int j = 0; j < 4; ++j) {
            const int row = (bp << 5) + (wr << 4) + (kq << 2) + j;
            const float v = fmaxf(acc[j] + bv, 0.0f);
            Cout[((((size_t)(row >> 6) << 2) + kcn) * 8 + kb2) * 512
                 + (size_t)(row & 63) * 8 + e2] = f2bf(v);
        }
    } else {
        #pragma unroll
        for (int j = 0; j < 4; ++j) {
            const int row = (bp << 5) + (wr << 4) + (kq << 2) + j;
            Cout[(size_t)row * 512 + C] = f2bf(acc[j] + bv);
        }
    }
}

// ---------------------------------------------------------------------------
// edge_z (2048 edge + 128 fill = 2176 blocks):
//   blocks [0,2048):    v[e] = exp(score[e]) (no max-sub; |s| = O(1)),
//                       block-partial Z -> part[cb] (only l5==0 lanes add).
//   blocks [2048,2176): fill shard 3
// ---------------------------------------------------------------------------
__global__ __launch_bounds__(256)
void edge_z(const u16* __restrict__ AB, const int* __restrict__ idx,
            const float* __restrict__ We2, const float* __restrict__ be2p,
            float* __restrict__ vbuf, float* __restrict__ part,
            float4* __restrict__ out4)
{
    const int bid = blockIdx.x;
    const int tid = threadIdx.x;

    if (bid >= 2048) {
        fill_shard(out4, 3, bid - 2048, tid);
        return;
    }

    __shared__ float sm[256];
    const int cb   = bid;                        // 0..2047
    const int lane = tid & 63;
    const int sub  = lane >> 5;
    const int l5   = lane & 31;
    const int wid  = (cb * 256 + tid) >> 6;      // 0..8191
    const float be2 = be2p[0];

    float w2v[8];
    #pragma unroll
    for (int q = 0; q < 2; ++q) {
        const float4 w = ((const float4*)We2)[l5 * 2 + q];
        w2v[q * 4 + 0] = w.x; w2v[q * 4 + 1] = w.y;
        w2v[q * 4 + 2] = w.z; w2v[q * 4 + 3] = w.w;
    }

    float zloc = 0.0f;
    #pragma unroll
    for (int it = 0; it < 8; ++it) {
        const int e = (wid << 1) + sub + (it << 14);    // covers [0, 131072)
        const int src = idx[2 * e];
        const int dst = idx[2 * e + 1];
        const uint4 av = *(const uint4*)(AB + ((size_t)src << 9) + (l5 << 3));
        const uint4 bv = *(const uint4*)(AB + ((size_t)dst << 9) + 256 + (l5 << 3));
        const u32 aw[4] = {av.x, av.y, av.z, av.w};
        const u32 bw[4] = {bv.x, bv.y, bv.z, bv.w};
        float p = 0.0f;
        #pragma unroll
        for (int q = 0; q < 4; ++q) {
            p += fmaxf(bflo(aw[q]) + bflo(bw[q]), 0.0f) * w2v[2 * q];
            p += fmaxf(bfhi(aw[q]) + bfhi(bw[q]), 0.0f) * w2v[2 * q + 1];
        }
        #pragma unroll
        for (int m = 16; m > 0; m >>= 1)
            p += __shfl_xor(p, m, 64);   // xor<32: stays within the half-wave
        const float v = expf(p + be2);
        if (l5 == 0) {
            vbuf[e] = v;
            zloc += v;                   // one lane per edge contributes
        }
    }
    sm[tid] = zloc;
    __syncthreads();
    for (int st = 128; st > 0; st >>= 1) {
        if (tid < st) sm[tid] += sm[tid + st];
        __syncthreads();
    }
    if (tid == 0) part[cb] = sm[0];
}

// fused: finalize Z over part[2048] (redundant per block) + scatter probs
__global__ __launch_bounds__(256)
void scatter_probs(const float* __restrict__ vbuf, const int* __restrict__ idx,
                   const float* __restrict__ part, float* __restrict__ out, int n)
{
    __shared__ float sm[256];
    float a = part[threadIdx.x];
    #pragma unroll
    for (int k = 1; k < 8; ++k)
        a += part[threadIdx.x + k * 256];
    sm[threadIdx.x] = a;
    __syncthreads();
    for (int st = 128; st > 0; st >>= 1) {
        if (threadIdx.x < st) sm[threadIdx.x] += sm[threadIdx.x + st];
        __syncthreads();
    }
    const float Z = sm[0];
    const int e = blockIdx.x * 256 + threadIdx.x;
    if (e < n)
        out[(size_t)idx[2 * e] * N_NODES + idx[2 * e + 1]] = vbuf[e] / Z;
}

// ---------------------------------------------------------------------------
extern "C" void kernel_launch(void* const* d_in, const int* in_sizes, int n_in,
                              void* d_out, int out_size, void* d_ws, size_t ws_size,
                              hipStream_t stream)
{
    const float* ideal = (const float*)d_in[0];   // 4096 x 1024
    const int*   idx   = (const int*)d_in[1];     // E x 2
    const float* W1    = (const float*)d_in[2];   // 256 x 1024
    const float* b1    = (const float*)d_in[3];   // 256
    const float* W2    = (const float*)d_in[4];   // 256 x 256
    const float* b2    = (const float*)d_in[5];   // 256
    const float* We1   = (const float*)d_in[6];   // 256 x 512
    const float* be1   = (const float*)d_in[7];   // 256
    const float* We2   = (const float*)d_in[8];   // 256
    const float* be2   = (const float*)d_in[9];   // 1
    float* out = (float*)d_out;

    char* Wb = (char*)d_ws;
    u16*   xh   = (u16*)(Wb);                          // 8 MB packed x
    u16*   w1h  = (u16*)(Wb + (8u << 20));             // 512 KB packed W1
    u16*   wabh = (u16*)(Wb + (8u << 20) + (512u << 10)); // 256 KB packed Wab
    u16*   h1h  = (u16*)(Wb + (9u << 20));             // 2 MB packed h1
    float* bab  = (float*)(Wb + (11u << 20));          // 2 KB
    u16*   ABbf = (u16*)(Wb + (12u << 20));            // 4 MB bf16 AB row-major
    float* vbuf = (float*)(Wb + (16u << 20));          // 512 KB exp(scores)
    float* part = vbuf + E_EDGES;                      // 2048 partial Z

    // pack + fold (+ fill shard 0)
    prep_all<<<2370, 256, 0, stream>>>(ideal, W1, We1, W2, b2, be1,
                                       xh, w1h, wabh, bab, (float4*)out);

    // h1 packed = relu(x @ W1.T + b1)   (1024 work blocks + fill shard 1)
    mfma_gemm32<16, 0, 8, 1><<<dim3(128, 9), 256, 0, stream>>>(
        xh, w1h, b1, h1h, (float4*)out);
    // AB bf16 = h1 @ Wab.T + bab        (2048 work blocks + fill shard 2)
    mfma_gemm32<4, 1, 16, 2><<<dim3(128, 17), 256, 0, stream>>>(
        h1h, wabh, bab, ABbf, (float4*)out);

    // edge scores + partial Z (+ fill shard 3)
    edge_z<<<2176, 256, 0, stream>>>(ABbf, idx, We2, be2, vbuf, part, (float4*)out);
    // Z finalize (redundant per block) + scatter
    scatter_probs<<<512, 256, 0, stream>>>(vbuf, idx, part, out, E_EDGES);
}